// Round 7
// baseline (541.409 us; speedup 1.0000x reference)
//
#include <hip/hip_runtime.h>

typedef __bf16 bf16;
typedef __attribute__((ext_vector_type(4))) float f32x4;
typedef __attribute__((ext_vector_type(8))) __bf16 bf16x8;
typedef __attribute__((ext_vector_type(4))) __bf16 bf16x4;
typedef __attribute__((ext_vector_type(4))) int i32x4;

#define NN 8192
#define FI 512
#define FO 256
#define NSPLIT 8
#define JCHUNK (NN / NSPLIT)
#define KSTEPS (JCHUNK / 32)
#define LOG2E 1.4426950408889634f

// ---------------------------------------------------------------------------
// k0 v3: adj (int32, 268 MB) -> byte-mask (8 MB). Memcpy-grade streaming:
// each lane reads 32 B CONTIGUOUS (2 x i32x4; wave = 2 KB contiguous) and
// writes 1 byte (wave = 64 B contiguous). No shfl, no strides. 32768 blocks.
// bit u of maskb[g] = (adj[g*8+u] > 0).
// ---------------------------------------------------------------------------
__global__ __launch_bounds__(256) void k0_pack(const int* __restrict__ adj,
                                               unsigned char* __restrict__ maskb) {
  const size_t gid = (size_t)blockIdx.x * 256 + threadIdx.x;
  const int* p = adj + gid * 8;
  i32x4 v0 = *(const i32x4*)(p);
  i32x4 v1 = *(const i32x4*)(p + 4);
  unsigned m = (unsigned)(v0.x > 0) | ((unsigned)(v0.y > 0) << 1) |
               ((unsigned)(v0.z > 0) << 2) | ((unsigned)(v0.w > 0) << 3) |
               ((unsigned)(v1.x > 0) << 4) | ((unsigned)(v1.y > 0) << 5) |
               ((unsigned)(v1.z > 0) << 6) | ((unsigned)(v1.w > 0) << 7);
  maskb[gid] = (unsigned char)m;
}

// ---------------------------------------------------------------------------
// kw: W [512][256] f32 -> Wt_hi/Wt_lo [256][512] bf16 (transposed + split).
// ---------------------------------------------------------------------------
__global__ __launch_bounds__(256) void kw_split(const float* __restrict__ W,
                                                bf16* __restrict__ wth,
                                                bf16* __restrict__ wtl) {
  const int idx = blockIdx.x * 256 + threadIdx.x;
  const int k = idx >> 8, n = idx & 255;
  float x = W[idx];
  bf16 hi = (bf16)x;
  wth[(size_t)n * FI + k] = hi;
  wtl[(size_t)n * FI + k] = (bf16)(x - (float)hi);
}

// ---------------------------------------------------------------------------
// k1: Wh = h @ W + bW via split-bf16 MFMA (hi*hi + hi*lo + lo*hi, fp32 acc).
// Writes whb bf16 fragment-major [i/32][n][i%32]; atomics for f1/f2.
// [proven R2/R4/R5/R6]
// ---------------------------------------------------------------------------
__global__ __launch_bounds__(256) void k1_gemm(
    const float* __restrict__ h, const bf16* __restrict__ wth,
    const bf16* __restrict__ wtl, const float* __restrict__ bW,
    const float* __restrict__ a1, const float* __restrict__ a2,
    bf16* __restrict__ whb, float* __restrict__ f1, float* __restrict__ f2) {
  __shared__ bf16 Ah[32 * 40];
  __shared__ bf16 Al[32 * 40];
  const int t = threadIdx.x;
  const int lane = t & 63, w = t >> 6;
  const int m16 = lane & 15, q = lane >> 4;
  const int bi = blockIdx.x, bj = blockIdx.y;
  const int i0 = bi * 32;
  const int n0 = bj * 128 + w * 32;
  const int srow = t >> 3, skoff = (t & 7) * 4;

  const f32x4 z4 = {0.f, 0.f, 0.f, 0.f};
  f32x4 acc[2][2];
#pragma unroll
  for (int mt = 0; mt < 2; ++mt)
#pragma unroll
    for (int nt = 0; nt < 2; ++nt) acc[mt][nt] = z4;

  const float* hrow = h + (size_t)(i0 + srow) * FI + skoff;

  for (int kt = 0; kt < FI / 32; ++kt) {
    f32x4 hv = *(const f32x4*)(hrow + kt * 32);
    bf16x8 bh[2], bl[2];
#pragma unroll
    for (int nt = 0; nt < 2; ++nt) {
      const size_t woff = (size_t)(n0 + nt * 16 + m16) * FI + kt * 32 + q * 8;
      bh[nt] = *(const bf16x8*)(wth + woff);
      bl[nt] = *(const bf16x8*)(wtl + woff);
    }
    bf16x4 hh, hl;
#pragma unroll
    for (int x = 0; x < 4; ++x) {
      float v = hv[x];
      bf16 hi = (bf16)v;
      hh[x] = hi;
      hl[x] = (bf16)(v - (float)hi);
    }
    __syncthreads();
    *(bf16x4*)&Ah[srow * 40 + skoff] = hh;
    *(bf16x4*)&Al[srow * 40 + skoff] = hl;
    __syncthreads();
#pragma unroll
    for (int mt = 0; mt < 2; ++mt) {
      bf16x8 ah = *(const bf16x8*)&Ah[(mt * 16 + m16) * 40 + q * 8];
      bf16x8 al = *(const bf16x8*)&Al[(mt * 16 + m16) * 40 + q * 8];
#pragma unroll
      for (int nt = 0; nt < 2; ++nt) {
        acc[mt][nt] = __builtin_amdgcn_mfma_f32_16x16x32_bf16(ah, bh[nt], acc[mt][nt], 0, 0, 0);
        acc[mt][nt] = __builtin_amdgcn_mfma_f32_16x16x32_bf16(al, bh[nt], acc[mt][nt], 0, 0, 0);
        acc[mt][nt] = __builtin_amdgcn_mfma_f32_16x16x32_bf16(ah, bl[nt], acc[mt][nt], 0, 0, 0);
      }
    }
  }
  float f1p[2][4] = {}, f2p[2][4] = {};
#pragma unroll
  for (int nt = 0; nt < 2; ++nt) {
    const int n = n0 + nt * 16 + m16;
    const float bw = bW[n], av1 = a1[n], av2 = a2[n];
#pragma unroll
    for (int mt = 0; mt < 2; ++mt) {
#pragma unroll
      for (int reg = 0; reg < 4; ++reg) {
        float wh = acc[mt][nt][reg] + bw;
        const int il = mt * 16 + q * 4 + reg;
        whb[(size_t)bi * (FO * 32) + n * 32 + il] = (bf16)wh;
        f1p[mt][reg] += wh * av1;
        f2p[mt][reg] += wh * av2;
      }
    }
  }
#pragma unroll
  for (int m = 1; m < 16; m <<= 1) {
#pragma unroll
    for (int mt = 0; mt < 2; ++mt)
#pragma unroll
      for (int reg = 0; reg < 4; ++reg) {
        f1p[mt][reg] += __shfl_xor(f1p[mt][reg], m);
        f2p[mt][reg] += __shfl_xor(f2p[mt][reg], m);
      }
  }
  if (m16 == 0) {
#pragma unroll
    for (int mt = 0; mt < 2; ++mt)
#pragma unroll
      for (int reg = 0; reg < 4; ++reg) {
        const int i = i0 + mt * 16 + q * 4 + reg;
        atomicAdd(&f1[i], f1p[mt][reg]);
        atomicAdd(&f2[i], f2p[mt][reg]);
      }
  }
}

// ---------------------------------------------------------------------------
// k3: Mstar = max_j f2[j]; also emits f2L[j] = f2[j] * log2(e) so k4's exp
// path needs no separate sub/mul (base-2 exp with pre-scaled args).
// ---------------------------------------------------------------------------
__global__ __launch_bounds__(256) void k3_max(const float* __restrict__ f2,
                                              float* __restrict__ f2L,
                                              float* __restrict__ Mstar) {
  __shared__ float red[4];
  const int t = threadIdx.x;
  float m = -1e30f;
  for (int i = t; i < NN; i += 256) {
    float v = f2[i];
    f2L[i] = v * LOG2E;
    m = fmaxf(m, v);
  }
#pragma unroll
  for (int d = 1; d < 64; d <<= 1) m = fmaxf(m, __shfl_xor(m, d));
  if ((t & 63) == 0) red[t >> 6] = m;
  __syncthreads();
  if (t == 0) *Mstar = fmaxf(fmaxf(red[0], red[1]), fmaxf(red[2], red[3]));
}

// ---------------------------------------------------------------------------
// k4 v8: barrier-free fused masked-softmax GEMM partial on the BYTE MASK.
// vs v6: (a) adj stream replaced by L1/L2-hot mask bytes (k0 pays the HBM
// cost at streaming BW instead); (b) tile re-shaped to 32 rows x 128 cols
// per wave (af 2, bfr 8) so score redundancy is x2 instead of x4 (VALU /2);
// (c) exp path compressed: val = exp2(max(A, fma(0.2,A,c2))) with
// A = ciLs + f2L[j], all shift/log2e algebra pre-folded (4 VALU/elem).
// FIFO order per step: [bfr_k(8)] [mask/f2L k+1 (4)] [pv from k-1 regs:
// waits oldest only] [MFMA: waits bfr_k, prefetch stays in flight].
// Scores computed directly in MFMA A-fragment layout (lane(m16,q) ->
// P[row=..+m16][j0+q*8..+7]); no LDS, no __syncthreads.
// ---------------------------------------------------------------------------
__global__ __launch_bounds__(256, 2) void k4_attn(
    const unsigned char* __restrict__ maskb, const bf16* __restrict__ whb,
    const float* __restrict__ f1, const float* __restrict__ f2L,
    const float* __restrict__ Mstar, const float* __restrict__ ba_p,
    float* __restrict__ acc_part, float* __restrict__ l_part) {
  const int t = threadIdx.x;
  const int lane = t & 63, w = t >> 6;
  const int m16 = lane & 15, q = lane >> 4;
  const int rb = blockIdx.x, s = blockIdx.y;
  const int i0 = rb * 64;
  const int jq = q * 8;
  const int wr = w & 1;   // row-half of the 64-row block (32 rows)
  const int wc = w >> 1;  // col-half of the 256 cols (128 cols)

  const float ba = *ba_p;
  const float Ms = *Mstar;
  float ciLs[2], c2[2];
  const unsigned char* mrow[2];
#pragma unroll
  for (int rt = 0; rt < 2; ++rt) {
    const int r = i0 + wr * 32 + rt * 16 + m16;
    float ci = f1[r] + ba;
    float v = ci + Ms;
    float sh = fmaxf(v, 0.2f * v);  // LeakyReLU(c_i + Mstar) >= row max
    float shl = sh * LOG2E;
    ciLs[rt] = ci * LOG2E - shl;
    c2[rt] = -0.8f * shl;
    mrow[rt] = maskb + ((size_t)r << 10);  // NN/8 = 1024 bytes per row
  }

  const f32x4 z4 = {0.f, 0.f, 0.f, 0.f};
  f32x4 acc[2][8];  // [rt][cc]
#pragma unroll
  for (int rt = 0; rt < 2; ++rt)
#pragma unroll
    for (int cc = 0; cc < 8; ++cc) acc[rt][cc] = z4;
  float lreg[2] = {0.f, 0.f};

  const int sbase = s * JCHUNK;

  // ---- prologue: step-0 mask/f2L into cur registers ----
  int mcur[2];
#pragma unroll
  for (int rt = 0; rt < 2; ++rt) mcur[rt] = mrow[rt][(sbase >> 3) + q];
  f32x4 fa0 = *(const f32x4*)(f2L + sbase + jq);
  f32x4 fa1 = *(const f32x4*)(f2L + sbase + jq + 4);

  for (int kt = 0; kt < KSTEPS; ++kt) {
    const int j0 = sbase + kt * 32;

    // (1) B-fragments for THIS step (oldest loads of this iteration)
    bf16x8 bfr[8];
    const size_t bbase = (size_t)(j0 >> 5) * (FO * 32) + jq;
#pragma unroll
    for (int cc = 0; cc < 8; ++cc)
      bfr[cc] = *(const bf16x8*)(whb + bbase + (size_t)((wc * 8 + cc) * 16 + m16) * 32);

    // (2) prefetch NEXT step's mask/f2L (newest; stay in flight)
    const int ktn = (kt + 1 < KSTEPS) ? kt + 1 : kt;
    const int j0n = sbase + ktn * 32;
    int mnx[2];
#pragma unroll
    for (int rt = 0; rt < 2; ++rt) mnx[rt] = mrow[rt][(j0n >> 3) + q];
    f32x4 fa0n = *(const f32x4*)(f2L + j0n + jq);
    f32x4 fa1n = *(const f32x4*)(f2L + j0n + jq + 4);

    // (3) scores from cur regs -> A-fragments (4 VALU/elem + exp)
    bf16x8 af[2];
#pragma unroll
    for (int rt = 0; rt < 2; ++rt) {
      const int mb = mcur[rt];
      float pv[8];
#pragma unroll
      for (int x = 0; x < 4; ++x) {
        float A = ciLs[rt] + fa0[x];
        float e2 = fmaxf(A, fmaf(0.2f, A, c2[rt]));
        float val = __builtin_amdgcn_exp2f(e2);
        pv[x] = ((mb >> x) & 1) ? val : 0.f;
      }
#pragma unroll
      for (int x = 4; x < 8; ++x) {
        float A = ciLs[rt] + fa1[x - 4];
        float e2 = fmaxf(A, fmaf(0.2f, A, c2[rt]));
        float val = __builtin_amdgcn_exp2f(e2);
        pv[x] = ((mb >> x) & 1) ? val : 0.f;
      }
#pragma unroll
      for (int x = 0; x < 8; ++x) lreg[rt] += pv[x];
#pragma unroll
      for (int x = 0; x < 8; ++x) af[rt][x] = (bf16)pv[x];
    }

    // (4) 16 MFMAs — wait only bfr_k (prefetch remains outstanding)
#pragma unroll
    for (int rt = 0; rt < 2; ++rt)
#pragma unroll
      for (int cc = 0; cc < 8; ++cc)
        acc[rt][cc] = __builtin_amdgcn_mfma_f32_16x16x32_bf16(af[rt], bfr[cc], acc[rt][cc], 0, 0, 0);

    // (5) rotate
    mcur[0] = mnx[0]; mcur[1] = mnx[1];
    fa0 = fa0n; fa1 = fa1n;
  }

  // ---- row sums (lanes sharing a row differ only in q = lane bits 4,5) ----
#pragma unroll
  for (int rt = 0; rt < 2; ++rt) {
    float lr = lreg[rt];
    lr += __shfl_xor(lr, 16);
    lr += __shfl_xor(lr, 32);
    if (wc == 0 && q == 0)
      l_part[(size_t)s * NN + i0 + wr * 32 + rt * 16 + m16] = lr;
  }
  // ---- C/D: col = lane&15 (n), row = q*4+reg  [verified R1-R6] ----
  float* ap = acc_part + (size_t)s * ((size_t)NN * FO);
#pragma unroll
  for (int rt = 0; rt < 2; ++rt) {
#pragma unroll
    for (int cc = 0; cc < 8; ++cc) {
      const int n = (wc * 8 + cc) * 16 + m16;
#pragma unroll
      for (int reg = 0; reg < 4; ++reg) {
        const int r = i0 + wr * 32 + rt * 16 + q * 4 + reg;
        ap[(size_t)r * FO + n] = acc[rt][cc][reg];
      }
    }
  }
}

// ---------------------------------------------------------------------------
// k5: out[i][n] = (sum_s acc_part[s][i][n]) / (sum_s l_part[s][i])
// ---------------------------------------------------------------------------
__global__ __launch_bounds__(256) void k5_reduce(
    const float* __restrict__ accp, const float* __restrict__ lp,
    float* __restrict__ out) {
  const int idx = blockIdx.x * 256 + threadIdx.x;
  const int i = idx >> 6, n4 = (idx & 63) * 4;
  f32x4 sum = {0.f, 0.f, 0.f, 0.f};
  float l = 0.f;
#pragma unroll
  for (int s = 0; s < NSPLIT; ++s) {
    sum += *(const f32x4*)&accp[(size_t)s * ((size_t)NN * FO) + (size_t)i * FO + n4];
    l += lp[s * NN + i];
  }
  const float rl = 1.0f / l;
  f32x4 o = sum * rl;
  *(f32x4*)&out[(size_t)i * FO + n4] = o;
}

// ---------------------------------------------------------------------------
// Workspace: whb 4MB | f1 32KB | f2 32KB | f2L 32KB | Mstar 256B |
//            acc_part 64MB | l_part 256KB | maskb 8MB | wth 256KB | wtl 256KB
// total ~77 MB
// ---------------------------------------------------------------------------
extern "C" void kernel_launch(void* const* d_in, const int* in_sizes, int n_in,
                              void* d_out, int out_size, void* d_ws, size_t ws_size,
                              hipStream_t stream) {
  const float* h   = (const float*)d_in[0];
  const int*   adj = (const int*)d_in[1];
  const float* W   = (const float*)d_in[2];
  const float* bW  = (const float*)d_in[3];
  const float* a1  = (const float*)d_in[4];
  const float* a2  = (const float*)d_in[5];
  const float* ba  = (const float*)d_in[6];
  float* out = (float*)d_out;

  char* ws = (char*)d_ws;
  bf16* whb   = (bf16*)ws;
  float* f1   = (float*)(ws + 4u * 1024 * 1024);
  float* f2   = (float*)(ws + 4u * 1024 * 1024 + 32 * 1024);
  float* f2L  = (float*)(ws + 4u * 1024 * 1024 + 64 * 1024);
  float* Mst  = (float*)(ws + 4u * 1024 * 1024 + 96 * 1024);
  float* accp = (float*)(ws + 4u * 1024 * 1024 + 96 * 1024 + 256);
  float* lp   = accp + (size_t)NSPLIT * NN * FO;
  unsigned char* maskb = (unsigned char*)((char*)lp + (size_t)NSPLIT * NN * 4);
  bf16* wth   = (bf16*)((char*)maskb + (size_t)NN * (NN / 8));
  bf16* wtl   = wth + (size_t)FO * FI;

  hipMemsetAsync(f1, 0, 64 * 1024, stream);  // zero f1+f2 (atomic targets)

  k0_pack<<<NN * NN / 8 / 256, 256, 0, stream>>>(adj, maskb);
  kw_split<<<FI * FO / 256, 256, 0, stream>>>(W, wth, wtl);
  k1_gemm<<<dim3(NN / 32, 2), 256, 0, stream>>>(h, wth, wtl, bW, a1, a2, whb, f1, f2);
  k3_max<<<1, 256, 0, stream>>>(f2, f2L, Mst);
  k4_attn<<<dim3(NN / 64, NSPLIT), 256, 0, stream>>>(maskb, whb, f1, f2L, Mst, ba, accp, lp);
  k5_reduce<<<(NN * FO / 4) / 256, 256, 0, stream>>>(accp, lp, out);
}